// Round 12
// baseline (701.511 us; speedup 1.0000x reference)
//
#include <hip/hip_runtime.h>
#include <math.h>

#define DD    64
#define TT    256
#define NROW  4096
#define BLK   64          // ONE wave per block: no barriers anywhere in the scan
#define GRID  256         // 256 row-tiles of 16 rows, 1 block (=1 wave) per CU

typedef __attribute__((ext_vector_type(8))) short  short8;
typedef __attribute__((ext_vector_type(4))) float  f32x4;

__device__ __forceinline__ float fexp2(float x) {
  float r;
  asm("v_exp_f32 %0, %1" : "=v"(r) : "v"(x));
  return r;
}
// packed f32->bf16 (RNE), 1 instruction for 2 values
__device__ __forceinline__ unsigned cvtpk(float lo, float hi) {
  unsigned r;
  asm("v_cvt_pk_bf16_f32 %0, %1, %2" : "=v"(r) : "v"(lo), "v"(hi));
  return r;
}
__device__ __forceinline__ unsigned short f2bf1(float f) {
  return (unsigned short)cvtpk(f, f);
}
__device__ __forceinline__ short8 pack_frag(f32x4 a, f32x4 b) {
  union { unsigned u[4]; short8 s; } z;
  z.u[0] = cvtpk(a[0], a[1]); z.u[1] = cvtpk(a[2], a[3]);
  z.u[2] = cvtpk(b[0], b[1]); z.u[3] = cvtpk(b[2], b[3]);
  return z.s;
}
__device__ __forceinline__ short8 load_wfrag(const float* p) {
  f32x4 a = *(const f32x4*)p;
  f32x4 b = *(const f32x4*)(p + 4);
  return pack_frag(a, b);
}
__device__ __forceinline__ short8 load_wfrag_s(const float* p, float s) {
  f32x4 a = *(const f32x4*)p * s;
  f32x4 b = *(const f32x4*)(p + 4) * s;
  return pack_frag(a, b);
}
// A&S 7.1.26 erf, max abs err 1.5e-7
__device__ __forceinline__ float ferf(float x) {
  float ax = fabsf(x);
  float t  = __builtin_amdgcn_rcpf(fmaf(0.3275911f, ax, 1.0f));
  float p  = fmaf(1.061405429f, t, -1.453152027f);
  p = fmaf(p, t, 1.421413741f);
  p = fmaf(p, t, -0.284496736f);
  p = fmaf(p, t, 0.254829592f);
  p = p * t;
  float y = 1.0f - p * fexp2(ax * ax * -1.44269504f);
  return copysignf(y, x);
}

#define SC_RZ (-1.44269504f)
#define SC_N  ( 2.88539008f)

// bias2[t][kh*16 + jt*4 + i] = msg bias for feature j = jt*16 + 4*kh + i
// (pre-permuted so the scan wave loads one f32x4 per jt, per its kh)
__global__ void bias2_kernel(const float* __restrict__ msg_W,
                             const float* __restrict__ msg_b,
                             const float* __restrict__ freq,
                             const float* __restrict__ phase,
                             float* __restrict__ bias2) {
  __shared__ float teL[DD];
  const int t = blockIdx.x;
  const int j = threadIdx.x;
  teL[j] = cosf(fmaf((float)t, freq[j], phase[j]));
  __syncthreads();
  float acc = msg_b[j];
  const float* wrow = msg_W + j * 192 + 128;
  #pragma unroll 8
  for (int k = 0; k < DD; ++k) acc = fmaf(teL[k], wrow[k], acc);
  const int jt = j >> 4, jj = j & 15;
  const int kh = jj >> 2, i = jj & 3;
  bias2[t * DD + kh * 16 + jt * 4 + i] = acc;
}

__launch_bounds__(BLK, 1)
__global__ void scan12(const float* __restrict__ x,
                       const int*   __restrict__ mask,
                       const float* __restrict__ msg_W,
                       const float* __restrict__ W_ih,
                       const float* __restrict__ W_hh,
                       const float* __restrict__ b_ih,
                       const float* __restrict__ b_hh,
                       const float* __restrict__ bias2,
                       float* __restrict__ out) {
  // all LDS is private to the single wave: ordering via lgkmcnt only
  __shared__ alignas(16) unsigned short whh_l[192 * 72]; // W_hh scaled bf16 rows (A-frags)
  __shared__ unsigned int SP[544];                       // s^T bf16 pairs: [n>>1]*17 + r
  __shared__ unsigned int MP[544];                       // msg^T bf16 pairs: [j>>1]*17 + r
  __shared__ alignas(16) float outT[16 * 68];            // fp32 state [r][n] for coalesced out
  __shared__ alignas(16) float biasL[4 * 64];            // gate biases (scaled)

  const int lane = threadIdx.x;
  const int r16  = lane & 15;
  const int kh   = lane >> 4;
  const int row0 = blockIdx.x * 16;

  // ---- one-time: gate-bias table ----
  {
    biasL[lane]       = (b_ih[lane]       + b_hh[lane])       * SC_RZ; // r
    biasL[64 + lane]  = (b_ih[64 + lane]  + b_hh[64 + lane])  * SC_RZ; // z
    biasL[128 + lane] =  b_ih[128 + lane] * SC_N;                      // n (ih)
    biasL[192 + lane] =  b_hh[128 + lane] * SC_N;                      // n (hh)
  }
  // ---- one-time: W_hh -> LDS (scaled bf16, row-major stride 72) ----
  for (int q = 0; q < 192; ++q) {
    float v = W_hh[q * 64 + lane] * ((q < 128) ? SC_RZ : SC_N);
    whh_l[q * 72 + lane] = f2bf1(v);
  }
  // ---- one-time: weight A-frags in registers ----
  short8 wmx[4][2], wms[4][2], wia[3][4][2];
  #pragma unroll
  for (int jt = 0; jt < 4; ++jt) {
    const float* mrow = msg_W + (size_t)(jt * 16 + r16) * 192;
    #pragma unroll
    for (int ks = 0; ks < 2; ++ks) {
      wmx[jt][ks] = load_wfrag(mrow + ks * 32 + kh * 8);        // x-part k
      wms[jt][ks] = load_wfrag(mrow + 64 + ks * 32 + kh * 8);   // s-part k
    }
  }
  {
    const float sc[3] = {SC_RZ, SC_RZ, SC_N};
    #pragma unroll
    for (int p = 0; p < 3; ++p)
      #pragma unroll
      for (int qt = 0; qt < 4; ++qt) {
        const float* irow = W_ih + (size_t)(p * 64 + qt * 16 + r16) * 64;
        #pragma unroll
        for (int ks = 0; ks < 2; ++ks)
          wia[p][qt][ks] = load_wfrag_s(irow + ks * 32 + kh * 8, sc[p]);
      }
  }

  // ---- s0 = mean over t; lane owns (row r16, features kh*16..kh*16+15) ----
  {
    f32x4 ac[4][2] = {{{0,0,0,0},{0,0,0,0}},{{0,0,0,0},{0,0,0,0}},
                      {{0,0,0,0},{0,0,0,0}},{{0,0,0,0},{0,0,0,0}}};
    const float* px = x + (size_t)(row0 + r16) * DD + kh * 16;
    const size_t tstep = (size_t)NROW * DD;
    #pragma unroll 4
    for (int t = 0; t < TT; t += 2) {
      const float* p0 = px + (size_t)t * tstep;
      const float* p1 = p0 + tstep;
      #pragma unroll
      for (int c = 0; c < 4; ++c) {
        ac[c][0] += *(const f32x4*)(p0 + c * 4);
        ac[c][1] += *(const f32x4*)(p1 + c * 4);
      }
    }
    #pragma unroll
    for (int c = 0; c < 4; ++c) {
      f32x4 m = (ac[c][0] + ac[c][1]) * (1.0f / 256.0f);
      *(f32x4*)&outT[r16 * 68 + kh * 16 + c * 4] = m;
      SP[(kh * 8 + c * 2 + 0) * 17 + r16] = cvtpk(m[0], m[1]);
      SP[(kh * 8 + c * 2 + 1) * 17 + r16] = cvtpk(m[2], m[3]);
    }
  }
  // fp32 state regs: s_f[qt][i] = s[r16][qt*16+4*kh+i] (redistribute via outT)
  f32x4 s_f[4];
  #pragma unroll
  for (int qt = 0; qt < 4; ++qt)
    s_f[qt] = *(const f32x4*)&outT[r16 * 68 + qt * 16 + 4 * kh];

  // ---- pipelines: x 2-deep, bias2 1-deep ----
  int tr1 = 1 * mask[1];   // tr[t+1] (bias prefetch)
  int tr2 = 2 * mask[2];   // tr[t+2] (x prefetch)
  f32x4 XA[4], XB[4], BA[4], BB[4];
  {
    const float* p0 = x + (size_t)(row0 + r16) * DD + kh * 8;          // tr[0]=0
    XA[0] = *(const f32x4*)p0;        XA[1] = *(const f32x4*)(p0 + 4);
    XA[2] = *(const f32x4*)(p0 + 32); XA[3] = *(const f32x4*)(p0 + 36);
    const float* p1 = x + ((size_t)tr1 * NROW + row0 + r16) * DD + kh * 8;
    XB[0] = *(const f32x4*)p1;        XB[1] = *(const f32x4*)(p1 + 4);
    XB[2] = *(const f32x4*)(p1 + 32); XB[3] = *(const f32x4*)(p1 + 36);
    const float* pb = bias2 + kh * 16;                                  // t=0
    #pragma unroll
    for (int jt = 0; jt < 4; ++jt) BA[jt] = *(const f32x4*)(pb + jt * 4);
  }

  auto body = [&](int t, f32x4 (&xu)[4], f32x4 (&bu)[4], f32x4 (&bl)[4]) {
    // off-chain: out store of t-1 from outT (before this step's gates rewrite it)
    if (t > 0) {
      #pragma unroll
      for (int q = 0; q < 4; ++q) {
        f32x4 ov = *(const f32x4*)&outT[(q * 4 + kh) * 68 + r16 * 4];
        *(f32x4*)(out + ((size_t)(t - 1) * NROW + row0 + q * 4 + kh) * DD + r16 * 4) = ov;
      }
    }
    // pack x B-frags (xu holds x[tr[t]]), then refill xu with x[tr[t+2]]
    short8 xB0 = pack_frag(xu[0], xu[1]);
    short8 xB1 = pack_frag(xu[2], xu[3]);
    {
      const float* pn = x + ((size_t)tr2 * NROW + row0 + r16) * DD + kh * 8;
      xu[0] = *(const f32x4*)pn;        xu[1] = *(const f32x4*)(pn + 4);
      xu[2] = *(const f32x4*)(pn + 32); xu[3] = *(const f32x4*)(pn + 36);
    }
    // bias2(t+1) prefetch into bl
    {
      const float* pb = bias2 + (size_t)tr1 * DD + kh * 16;
      #pragma unroll
      for (int jt = 0; jt < 4; ++jt) bl[jt] = *(const f32x4*)(pb + jt * 4);
    }
    tr1 = tr2;
    {
      int t3 = t + 3;
      tr2 = (t3 < TT) ? t3 * mask[t3] : 0;
    }

    // s^T B-frags from SP (state s_{t-1})
    short8 sB0, sB1;
    {
      union { unsigned u[4]; short8 s; } z0, z1;
      const int base = 4 * kh * 17 + r16;
      #pragma unroll
      for (int w = 0; w < 4; ++w) {
        z0.u[w] = SP[base + w * 17];              // k = 8kh+2w (+1)
        z1.u[w] = SP[base + (16 + w) * 17];       // k = 32+8kh+2w
      }
      sB0 = z0.s; sB1 = z1.s;
    }

    // gh^T = Whh_scaled @ s^T  (A from LDS, C-init = n-gate hh bias)
    f32x4 ghC[4][3];
    #pragma unroll
    for (int qt = 0; qt < 4; ++qt) {
      f32x4 bnh = *(const f32x4*)&biasL[192 + qt * 16 + 4 * kh];
      #pragma unroll
      for (int p = 0; p < 3; ++p) {
        const unsigned short* wrow = &whh_l[(p * 64 + qt * 16 + r16) * 72];
        short8 a0 = *(const short8*)(wrow + kh * 8);
        short8 a1 = *(const short8*)(wrow + 32 + kh * 8);
        f32x4 c = (p == 2) ? bnh : f32x4{0.f, 0.f, 0.f, 0.f};
        c = __builtin_amdgcn_mfma_f32_16x16x32_bf16(a0, sB0, c, 0, 0, 0);
        c = __builtin_amdgcn_mfma_f32_16x16x32_bf16(a1, sB1, c, 0, 0, 0);
        ghC[qt][p] = c;
      }
    }

    // msg^T = Wm @ [x|s]^T  (16 MFMAs), + bias2, GELU, pack -> MP
    #pragma unroll
    for (int jt = 0; jt < 4; ++jt) {
      f32x4 c = {0.f, 0.f, 0.f, 0.f};
      c = __builtin_amdgcn_mfma_f32_16x16x32_bf16(wmx[jt][0], xB0, c, 0, 0, 0);
      c = __builtin_amdgcn_mfma_f32_16x16x32_bf16(wmx[jt][1], xB1, c, 0, 0, 0);
      c = __builtin_amdgcn_mfma_f32_16x16x32_bf16(wms[jt][0], sB0, c, 0, 0, 0);
      c = __builtin_amdgcn_mfma_f32_16x16x32_bf16(wms[jt][1], sB1, c, 0, 0, 0);
      float g0, g1, g2, g3;
      {
        float a0 = c[0] + bu[jt][0], a1 = c[1] + bu[jt][1];
        float a2 = c[2] + bu[jt][2], a3 = c[3] + bu[jt][3];
        g0 = 0.5f * a0 * (1.0f + ferf(a0 * 0.70710678118654752f));
        g1 = 0.5f * a1 * (1.0f + ferf(a1 * 0.70710678118654752f));
        g2 = 0.5f * a2 * (1.0f + ferf(a2 * 0.70710678118654752f));
        g3 = 0.5f * a3 * (1.0f + ferf(a3 * 0.70710678118654752f));
      }
      MP[(jt * 8 + 2 * kh + 0) * 17 + r16] = cvtpk(g0, g1);
      MP[(jt * 8 + 2 * kh + 1) * 17 + r16] = cvtpk(g2, g3);
    }

    // msg B-frags from MP (same-wave round trip; lgkmcnt ordering)
    short8 mB0, mB1;
    {
      union { unsigned u[4]; short8 s; } z0, z1;
      const int base = 4 * kh * 17 + r16;
      #pragma unroll
      for (int w = 0; w < 4; ++w) {
        z0.u[w] = MP[base + w * 17];
        z1.u[w] = MP[base + (16 + w) * 17];
      }
      mB0 = z0.s; mB1 = z1.s;
    }

    // per qt: gi^T (C-init = combined biases) + gates + state/out updates
    #pragma unroll
    for (int qt = 0; qt < 4; ++qt) {
      f32x4 gR = *(const f32x4*)&biasL[qt * 16 + 4 * kh];
      f32x4 gZ = *(const f32x4*)&biasL[64 + qt * 16 + 4 * kh];
      f32x4 gN = *(const f32x4*)&biasL[128 + qt * 16 + 4 * kh];
      gR = __builtin_amdgcn_mfma_f32_16x16x32_bf16(wia[0][qt][0], mB0, gR, 0, 0, 0);
      gR = __builtin_amdgcn_mfma_f32_16x16x32_bf16(wia[0][qt][1], mB1, gR, 0, 0, 0);
      gZ = __builtin_amdgcn_mfma_f32_16x16x32_bf16(wia[1][qt][0], mB0, gZ, 0, 0, 0);
      gZ = __builtin_amdgcn_mfma_f32_16x16x32_bf16(wia[1][qt][1], mB1, gZ, 0, 0, 0);
      gN = __builtin_amdgcn_mfma_f32_16x16x32_bf16(wia[2][qt][0], mB0, gN, 0, 0, 0);
      gN = __builtin_amdgcn_mfma_f32_16x16x32_bf16(wia[2][qt][1], mB1, gN, 0, 0, 0);
      f32x4 sn;
      #pragma unroll
      for (int i = 0; i < 4; ++i) {
        float er = gR[i] + ghC[qt][0][i];
        float ez = gZ[i] + ghC[qt][1][i];
        float rg = __builtin_amdgcn_rcpf(1.0f + fexp2(er));
        float zg = __builtin_amdgcn_rcpf(1.0f + fexp2(ez));
        float yn = fmaf(rg, ghC[qt][2][i], gN[i]);
        float ng = 1.0f - 2.0f * __builtin_amdgcn_rcpf(1.0f + fexp2(yn));
        sn[i] = fmaf(zg, s_f[qt][i] - ng, ng);
      }
      s_f[qt] = sn;
      SP[(qt * 8 + 2 * kh + 0) * 17 + r16] = cvtpk(sn[0], sn[1]);
      SP[(qt * 8 + 2 * kh + 1) * 17 + r16] = cvtpk(sn[2], sn[3]);
      *(f32x4*)&outT[r16 * 68 + qt * 16 + 4 * kh] = sn;   // fp32 for out staging
    }
  };

  // statically role-swapped 2x unroll (rule #20)
  for (int tt = 0; tt < TT; tt += 2) {
    body(tt,     XA, BA, BB);
    body(tt + 1, XB, BB, BA);
  }
  // final output row (t = 255)
  #pragma unroll
  for (int q = 0; q < 4; ++q) {
    f32x4 ov = *(const f32x4*)&outT[(q * 4 + kh) * 68 + r16 * 4];
    *(f32x4*)(out + ((size_t)(TT - 1) * NROW + row0 + q * 4 + kh) * DD + r16 * 4) = ov;
  }
}

extern "C" void kernel_launch(void* const* d_in, const int* in_sizes, int n_in,
                              void* d_out, int out_size, void* d_ws, size_t ws_size,
                              hipStream_t stream) {
  const float* x      = (const float*)d_in[0];
  const int*   mask   = (const int*)  d_in[1];
  const float* msg_W  = (const float*)d_in[2];
  const float* msg_b  = (const float*)d_in[3];
  const float* W_ih   = (const float*)d_in[4];
  const float* W_hh   = (const float*)d_in[5];
  const float* b_ih   = (const float*)d_in[6];
  const float* b_hh   = (const float*)d_in[7];
  const float* freq   = (const float*)d_in[8];
  const float* phase  = (const float*)d_in[9];
  float* out   = (float*)d_out;
  float* bias2 = (float*)d_ws;   // TT*DD floats = 64 KB (permuted msg-bias table)

  (void)in_sizes; (void)n_in; (void)out_size; (void)ws_size;

  bias2_kernel<<<TT, DD, 0, stream>>>(msg_W, msg_b, freq, phase, bias2);
  scan12<<<GRID, BLK, 0, stream>>>(x, mask, msg_W, W_ih, W_hh,
                                   b_ih, b_hh, bias2, out);
}